// Round 10
// baseline (195.682 us; speedup 1.0000x reference)
//
#include <hip/hip_runtime.h>
#include <hip/hip_bf16.h>

// LinearShift forward:
//   out = q16(input) @ (exp2(round(shift))*sign(sign)).T + q16(bias)
// bf16 MFMA GEMM, 256x256 tile, BK=64, 16x16x32 MFMA.
// R10 structure: B DIRECT FROM GLOBAL (no B LDS), A in a TRIPLE-buffered ring.
//  - 8 waves (2Mx4N), 512 threads; per-wave 128x64; acc 128 VGPR
//  - A: 3 LDS slots x 32KB (96 KiB), staged via global_load_lds w=16 with
//    inverse-swizzled source; 3-bit XOR swizzle on ds_read (0 conflicts, R2 PMC)
//  - B: 8 x global 16B loads/wave/tile straight into MFMA operand regs
//    (B-panel is L2-resident across 16 M-blocks); reloaded after last use
//    per phase (ph2: r0-1, ph3: r2-3) -> no extra reg set
//  - sync per K-tile: ONE boundary barrier + ONE counted VMW(12)
//    (in flight = b(t+1) 8 + A(t+2) 4; A(t+2) targets slot last read at t-1
//    behind a barrier -> race-free without latency shields)
//  - s_setprio(1) around MFMA clusters; bijective XCD blockIdx swizzle

#define BM 256
#define BN 256
#define BK 64

typedef __bf16 bf16_t;
typedef __attribute__((ext_vector_type(8))) __bf16 bf16x8;
typedef __attribute__((ext_vector_type(4))) __bf16 bf16x4;
typedef __attribute__((ext_vector_type(4))) float f32x4;

__device__ __forceinline__ float q16(float x) {
    // floor-quantize to 2^-16 steps, clamp to [-2^15, 2^15 - 1]
    float f = floorf(x * 65536.0f) * (1.0f / 65536.0f);
    return fminf(fmaxf(f, -32768.0f), 32767.0f);
}

__global__ void quant_input_kernel(const float* __restrict__ in,
                                   bf16_t* __restrict__ out, int nvec) {
    int stride = gridDim.x * blockDim.x;
    for (int i = blockIdx.x * blockDim.x + threadIdx.x; i < nvec; i += stride) {
        float4 v = reinterpret_cast<const float4*>(in)[i];
        bf16x4 o;
        o[0] = (bf16_t)q16(v.x);
        o[1] = (bf16_t)q16(v.y);
        o[2] = (bf16_t)q16(v.z);
        o[3] = (bf16_t)q16(v.w);
        reinterpret_cast<bf16x4*>(out)[i] = o;
    }
}

__global__ void make_weight_kernel(const float* __restrict__ shift,
                                   const float* __restrict__ sign_,
                                   bf16_t* __restrict__ out, int nvec) {
    int stride = gridDim.x * blockDim.x;
    for (int i = blockIdx.x * blockDim.x + threadIdx.x; i < nvec; i += stride) {
        float4 sh = reinterpret_cast<const float4*>(shift)[i];
        float4 sg = reinterpret_cast<const float4*>(sign_)[i];
        float shs[4] = {sh.x, sh.y, sh.z, sh.w};
        float sgs[4] = {sg.x, sg.y, sg.z, sg.w};
        bf16x4 o;
#pragma unroll
        for (int j = 0; j < 4; ++j) {
            float s = fminf(fmaxf(sgs[j], -1.0f), 1.0f);
            float sv = (s > 0.0f) ? 1.0f : ((s < 0.0f) ? -1.0f : 0.0f);
            o[j] = (bf16_t)(exp2f(rintf(shs[j])) * sv);
        }
        reinterpret_cast<bf16x4*>(out)[i] = o;
    }
}

// ---- 256x256 bf16 GEMM: C[M][N] = A[M][K]*B[N][K]^T + q16(bias)[N]

#define VMW(N) asm volatile("s_waitcnt vmcnt(" #N ")" ::: "memory")
#define BARF() do { __builtin_amdgcn_s_barrier(); asm volatile("" ::: "memory"); } while (0)

// stage one A half (128 rows x 64 cols, 2 x global_load_lds w=16 per thread)
#define STAGE(LDSOFF, SRC) do {                                                          \
    const bf16_t* _s = (SRC);                                                            \
    bf16_t* _d = &lds[(LDSOFF)] + tid * 8;                                               \
    __builtin_amdgcn_global_load_lds((const __attribute__((address_space(1))) void*)_s,  \
                                     (__attribute__((address_space(3))) void*)_d,        \
                                     16, 0, 0);                                          \
    __builtin_amdgcn_global_load_lds(                                                    \
        (const __attribute__((address_space(1))) void*)(_s + (size_t)64 * K),            \
        (__attribute__((address_space(3))) void*)(_d + 4096), 16, 0, 0);                 \
} while (0)

// stage full A K-tile T into ring slot SLOT (4 loads/thread)
#define STAGE_A(SLOT, T) do {                                                            \
    STAGE((SLOT) * 16384 + 0,    srcA0 + (size_t)(T) * 64);                              \
    STAGE((SLOT) * 16384 + 8192, srcA1 + (size_t)(T) * 64);                              \
} while (0)

// read A fragments for row-half MH from ring slot base AB (8 x ds_read_b128)
#define READ_A8(AB, MH) do {                                                             \
    _Pragma("unroll") for (int m = 0; m < 4; ++m)                                        \
        _Pragma("unroll") for (int kk = 0; kk < 2; ++kk)                                 \
            af[m][kk] = *(const bf16x8*)&(AB)[wm * 8192 +                                \
                                             ((MH) * 64 + m * 16 + fr) * 64 +            \
                                             ((((kk << 2) | hi) ^ fr7) << 3)];           \
} while (0)

// load B fragment row-group R for K-tile T straight from global (2 x 16B)
#define LOADB(R, T) do {                                                                 \
    _Pragma("unroll") for (int kk = 0; kk < 2; ++kk)                                     \
        b[R][kk] = *(const bf16x8*)(gB##R + (size_t)(T) * 64 + kk * 32);                 \
} while (0)

// 16 MFMA = one C-quadrant x K=64; b row-groups r = NH*2+n
#define MQUAD(MH, NH) do {                                                               \
    __builtin_amdgcn_s_setprio(1);                                                       \
    _Pragma("unroll") for (int m = 0; m < 4; ++m)                                        \
        _Pragma("unroll") for (int n = 0; n < 2; ++n)                                    \
            _Pragma("unroll") for (int kk = 0; kk < 2; ++kk)                             \
                acc[(MH) * 4 + m][(NH) * 2 + n] =                                        \
                    __builtin_amdgcn_mfma_f32_16x16x32_bf16(                             \
                        af[m][kk], b[(NH) * 2 + n][kk],                                  \
                        acc[(MH) * 4 + m][(NH) * 2 + n], 0, 0, 0);                       \
    __builtin_amdgcn_s_setprio(0);                                                       \
} while (0)

// One K-tile: quadrants (0,0),(0,1),(1,0),(1,1). af0 read ph0, af1 ph2.
// b[0..1] last use ph2 -> reload for t+1 after; b[2..3] last use ph3 -> after.
// Stage A(t+2) at ph3 into slot S2 (last read at t-1, behind a barrier).
// Boundary: counted VMW keeps {b(t+1):8, A(t+2):4} in flight; drains A(t+1)
// (issued at t-1) -> next tile's ds_reads safe. One barrier per tile.
#define TILE(T, AB, S2, DO_B, DO_A, W) do {                                              \
    READ_A8(AB, 0);                                                                      \
    MQUAD(0, 0);                                                                         \
    MQUAD(0, 1);                                                                         \
    READ_A8(AB, 1);                                                                      \
    MQUAD(1, 0);                                                                         \
    if (DO_B) { LOADB(0, (T) + 1); LOADB(1, (T) + 1); }                                  \
    MQUAD(1, 1);                                                                         \
    if (DO_B) { LOADB(2, (T) + 1); LOADB(3, (T) + 1); }                                  \
    if (DO_A) STAGE_A(S2, (T) + 2);                                                      \
    if ((W) == 12) VMW(12);                                                              \
    else if ((W) == 8) VMW(8);                                                           \
    BARF();                                                                              \
} while (0)

__global__ __launch_bounds__(512, 2)
void gemm256_kernel(const bf16_t* __restrict__ A,
                    const bf16_t* __restrict__ B,
                    const float* __restrict__ bias,
                    float* __restrict__ C,
                    int M, int N, int K) {
    // 96 KiB: A ring, 3 slots x 16384 bf16 (256 rows x 64 cols)
    __shared__ bf16_t lds[49152];

    const int ntn = N / BN;
    const int nwg = gridDim.x;
    // bijective XCD swizzle (8 XCDs)
    const int q = nwg >> 3, r = nwg & 7;
    const int xcd = blockIdx.x & 7, lid = blockIdx.x >> 3;
    const int swz = (xcd < r ? xcd * (q + 1) : r * (q + 1) + (xcd - r) * q) + lid;
    const int tile_m = (swz / ntn) * BM;
    const int tile_n = (swz % ntn) * BN;

    const int tid = threadIdx.x;
    const int lane = tid & 63;
    const int wid = tid >> 6;
    const int wm = wid >> 2;   // 0..1: row half
    const int wn = wid & 3;    // 0..3: col quarter
    const int fr = lane & 15;
    const int hi = lane >> 4;
    const int fr7 = fr & 7;

    // A staging source (inverse-swizzled column; bytes 4-6 ^= row bits 0-2)
    const int colsrc_e = ((((tid & 7) * 16) ^ ((tid & 56) << 1)) >> 1);
    const bf16_t* srcA0 = A + (size_t)(tile_m + (tid >> 3)) * K + colsrc_e;
    const bf16_t* srcA1 = srcA0 + (size_t)128 * K;

    // B fragment bases: row-group r covers output col = wn*64 + r*16 + fr
    const bf16_t* gB0 = B + (size_t)(tile_n + wn * 64 + 0 * 16 + fr) * K + hi * 8;
    const bf16_t* gB1 = B + (size_t)(tile_n + wn * 64 + 1 * 16 + fr) * K + hi * 8;
    const bf16_t* gB2 = B + (size_t)(tile_n + wn * 64 + 2 * 16 + fr) * K + hi * 8;
    const bf16_t* gB3 = B + (size_t)(tile_n + wn * 64 + 3 * 16 + fr) * K + hi * 8;

    bf16x8 af[4][2], b[4][2];
    f32x4 acc[8][4] = {};

    // prologue: A slots 0,1 <- tiles 0,1 (8 loads); B frags for tile 0 (8);
    // VMW(12) drains A(t0), keeps {A(t1), b(t0)} in flight (b drained by
    // compiler's per-use vmcnt at first MFMA).
    STAGE_A(0, 0);
    STAGE_A(1, 1);
    LOADB(0, 0); LOADB(1, 0); LOADB(2, 0); LOADB(3, 0);
    VMW(12);
    BARF();

    // 64 K-tiles; ring slot scur = t%3, stage target s2 = (t+2)%3
    int scur = 0;
    for (int t = 0; t < 62; ++t) {
        const int s2 = scur >= 1 ? scur - 1 : scur + 2;   // (t+2)%3
        const bf16_t* ab = &lds[scur * 16384];
        TILE(t, ab, s2, 1, 1, 12);
        scur = scur >= 2 ? 0 : scur + 1;
    }
    {   // t=62: b(63) only (8 in flight at boundary); drains A(63)
        const bf16_t* ab = &lds[scur * 16384];
        TILE(62, ab, 0, 1, 0, 8);
        scur = scur >= 2 ? 0 : scur + 1;
    }
    {   // t=63: no loads, no waits
        const bf16_t* ab = &lds[scur * 16384];
        READ_A8(ab, 0);
        MQUAD(0, 0);
        MQUAD(0, 1);
        READ_A8(ab, 1);
        MQUAD(1, 0);
        MQUAD(1, 1);
    }

    // epilogue: C/D layout col=lane&15, row=(lane>>4)*4+reg
    float qb[4];
#pragma unroll
    for (int ng = 0; ng < 4; ++ng)
        qb[ng] = q16(bias[tile_n + wn * 64 + ng * 16 + fr]);
#pragma unroll
    for (int mg = 0; mg < 8; ++mg) {
        const int grow0 = tile_m + wm * 128 + mg * 16 + hi * 4;
#pragma unroll
        for (int ng = 0; ng < 4; ++ng) {
            const int gcol = tile_n + wn * 64 + ng * 16 + fr;
#pragma unroll
            for (int rr = 0; rr < 4; ++rr)
                C[(size_t)(grow0 + rr) * N + gcol] = acc[mg][ng][rr] + qb[ng];
        }
    }
}

extern "C" void kernel_launch(void* const* d_in, const int* in_sizes, int n_in,
                              void* d_out, int out_size, void* d_ws, size_t ws_size,
                              hipStream_t stream) {
    const float* inp   = (const float*)d_in[0];
    const float* shift = (const float*)d_in[1];
    const float* sign_ = (const float*)d_in[2];
    const float* bias  = (const float*)d_in[3];
    float* out = (float*)d_out;

    const int OUT_F = in_sizes[3];              // 4096
    const int IN_F  = in_sizes[1] / OUT_F;      // 4096
    const int Mrows = in_sizes[0] / IN_F;       // 4096

    bf16_t* Aq = (bf16_t*)d_ws;
    bf16_t* Wq = Aq + (size_t)Mrows * IN_F;     // (M*K + N*K)*2 = 67.2 MB of ws

    const int nA = Mrows * IN_F;
    const int nW = OUT_F * IN_F;

    quant_input_kernel<<<2048, 256, 0, stream>>>(inp, Aq, nA >> 2);
    make_weight_kernel<<<2048, 256, 0, stream>>>(shift, sign_, Wq, nW >> 2);

    dim3 grid((Mrows / BM) * (OUT_F / BN));
    gemm256_kernel<<<grid, 512, 0, stream>>>(Aq, Wq, bias, out,
                                             Mrows, OUT_F, IN_F);
}

// Round 11
// 171.237 us; speedup vs baseline: 1.1428x; 1.1428x over previous
//
#include <hip/hip_runtime.h>
#include <hip/hip_bf16.h>

// LinearShift forward:
//   out = q16(input) @ (exp2(round(shift))*sign(sign)).T + q16(bias)
// bf16 MFMA GEMM, 256x256 tile, BK=64, 32x32x16 MFMA (m119: +17% vs 16x16),
// R7/R9 sync skeleton. R11 = R8 + CORRECTED swizzle + no lgkm pins.
//  - swizzle fix: slot(row,kq) = kq ^ ((row>>1)&3)  [R8 used lane&3 -> only 4
//    of 8 bank-groups within each 16-lane service group -> 3.8e7 conflicts.
//    With row bits 1-2: group = 4*(row&1) + (kq^((row>>1)&3)) covers all 8
//    groups exactly 2x per 16-lane group = conflict-free (R2's criterion)]
//  - staging inverse: koff = ((tid&3) ^ ((tid>>3)&3)) * 8
//  - K-SLICED slots A0/A1/B0/B1 (256 rows x 32 k); 2 barriers/tile (end-ph1
//    WAR fence + end-ph3 boundary after counted VMW(4)); staging spread
//    ph0:B1(t+1) ph1:A1(t+1) ph2:B0(t+2) ph3:A0(t+2)
//  - no manual lgkm waits (R9: compiler emits per-use lgkmcnt)
//  - s_setprio(1) around MFMA clusters; bijective XCD blockIdx swizzle

#define BM 256
#define BN 256
#define BK 64

typedef __bf16 bf16_t;
typedef __attribute__((ext_vector_type(8))) __bf16 bf16x8;
typedef __attribute__((ext_vector_type(4))) __bf16 bf16x4;
typedef __attribute__((ext_vector_type(16))) float f32x16;

__device__ __forceinline__ float q16(float x) {
    // floor-quantize to 2^-16 steps, clamp to [-2^15, 2^15 - 1]
    float f = floorf(x * 65536.0f) * (1.0f / 65536.0f);
    return fminf(fmaxf(f, -32768.0f), 32767.0f);
}

__global__ void quant_input_kernel(const float* __restrict__ in,
                                   bf16_t* __restrict__ out, int nvec) {
    int stride = gridDim.x * blockDim.x;
    for (int i = blockIdx.x * blockDim.x + threadIdx.x; i < nvec; i += stride) {
        float4 v = reinterpret_cast<const float4*>(in)[i];
        bf16x4 o;
        o[0] = (bf16_t)q16(v.x);
        o[1] = (bf16_t)q16(v.y);
        o[2] = (bf16_t)q16(v.z);
        o[3] = (bf16_t)q16(v.w);
        reinterpret_cast<bf16x4*>(out)[i] = o;
    }
}

__global__ void make_weight_kernel(const float* __restrict__ shift,
                                   const float* __restrict__ sign_,
                                   bf16_t* __restrict__ out, int nvec) {
    int stride = gridDim.x * blockDim.x;
    for (int i = blockIdx.x * blockDim.x + threadIdx.x; i < nvec; i += stride) {
        float4 sh = reinterpret_cast<const float4*>(shift)[i];
        float4 sg = reinterpret_cast<const float4*>(sign_)[i];
        float shs[4] = {sh.x, sh.y, sh.z, sh.w};
        float sgs[4] = {sg.x, sg.y, sg.z, sg.w};
        bf16x4 o;
#pragma unroll
        for (int j = 0; j < 4; ++j) {
            float s = fminf(fmaxf(sgs[j], -1.0f), 1.0f);
            float sv = (s > 0.0f) ? 1.0f : ((s < 0.0f) ? -1.0f : 0.0f);
            o[j] = (bf16_t)(exp2f(rintf(shs[j])) * sv);
        }
        reinterpret_cast<bf16x4*>(out)[i] = o;
    }
}

// ---- 256x256 bf16 GEMM (32x32x16): C[M][N] = A[M][K]*B[N][K]^T + q16(bias)[N]

#define VMW(N) asm volatile("s_waitcnt vmcnt(" #N ")" ::: "memory")
#define BARF() do { __builtin_amdgcn_s_barrier(); asm volatile("" ::: "memory"); } while (0)

// stage one k-slice slot (256 rows x 32 k = 16KB, 2 x global_load_lds w=16)
#define STAGE(LDSOFF, SRC) do {                                                          \
    const bf16_t* _s = (SRC);                                                            \
    bf16_t* _d = &lds[(LDSOFF)] + tid * 8;                                               \
    __builtin_amdgcn_global_load_lds((const __attribute__((address_space(1))) void*)_s,  \
                                     (__attribute__((address_space(3))) void*)_d,        \
                                     16, 0, 0);                                          \
    __builtin_amdgcn_global_load_lds(                                                    \
        (const __attribute__((address_space(1))) void*)(_s + (size_t)128 * K),           \
        (__attribute__((address_space(3))) void*)(_d + 4096), 16, 0, 0);                 \
} while (0)

// reads for k-step KS (0..3): A 4 x b128 + B 2 x b128; slot = kq ^ ((row>>1)&3)
// row reduces to l31 (frag row offsets are multiples of 32)
#define READ_AB(BUF, KS) do {                                                            \
    const bf16_t* _As = &lds[(BUF) * 32768 + ((KS) >> 1) * 8192];                        \
    const bf16_t* _Bs = &lds[(BUF) * 32768 + 16384 + ((KS) >> 1) * 8192];                \
    const int _p = ((((((KS) & 1) << 1) | hi2) ^ rsw) << 3);                             \
    _Pragma("unroll") for (int m = 0; m < 4; ++m)                                        \
        af[m] = *(const bf16x8*)&_As[(wm * 128 + m * 32 + l31) * 32 + _p];               \
    _Pragma("unroll") for (int n = 0; n < 2; ++n)                                        \
        bf[n] = *(const bf16x8*)&_Bs[(wn * 64 + n * 32 + l31) * 32 + _p];                \
} while (0)

// 8 MFMA = whole 128x64 wave-tile x K=16
#define MFMA8() do {                                                                     \
    __builtin_amdgcn_s_setprio(1);                                                       \
    _Pragma("unroll") for (int m = 0; m < 4; ++m)                                        \
        _Pragma("unroll") for (int n = 0; n < 2; ++n)                                    \
            acc[m][n] = __builtin_amdgcn_mfma_f32_32x32x16_bf16(                         \
                af[m], bf[n], acc[m][n], 0, 0, 0);                                       \
    __builtin_amdgcn_s_setprio(0);                                                       \
} while (0)

// One K-tile = 4 k-step phases (6 b128 reads each; compiler-scheduled lgkm).
// Staging: ph0 buf^1.B1<-t+1, ph1 buf^1.A1<-t+1 (slots last read at t's
// ph2/ph3... consumed next tile, behind boundary barrier); ph2 buf.B0<-t+2,
// ph3 buf.A0<-t+2 (slice-0 slots, last read ph1, behind mid barrier).
// Boundary VMW(4) keeps only t+2's B0/A0 in flight; drains all of t+1.
#define TILE(BUF, T, S01, S23, ENDW) do {                                                \
    /* ph0 */                                                                            \
    READ_AB(BUF, 0);                                                                     \
    if (S01) STAGE(((BUF) ^ 1) * 32768 + 24576, srcB + (size_t)((T) + 1) * 64 + 32);     \
    MFMA8();                                                                             \
    /* ph1 */                                                                            \
    READ_AB(BUF, 1);                                                                     \
    if (S01) STAGE(((BUF) ^ 1) * 32768 + 8192, srcA + (size_t)((T) + 1) * 64 + 32);      \
    MFMA8();                                                                             \
    BARF();   /* mid WAR fence: slice-0 reads complete before slice-0 stages */          \
    /* ph2 */                                                                            \
    READ_AB(BUF, 2);                                                                     \
    if (S23) STAGE((BUF) * 32768 + 16384, srcB + (size_t)((T) + 2) * 64);                \
    MFMA8();                                                                             \
    /* ph3 */                                                                            \
    READ_AB(BUF, 3);                                                                     \
    if (S23) STAGE((BUF) * 32768 + 0, srcA + (size_t)((T) + 2) * 64);                    \
    MFMA8();                                                                             \
    if ((ENDW) == 4) VMW(4);                                                             \
    else if ((ENDW) == 0) VMW(0);                                                        \
    BARF();   /* tile boundary */                                                        \
} while (0)

__global__ __launch_bounds__(512, 2)
void gemm256_kernel(const bf16_t* __restrict__ A,
                    const bf16_t* __restrict__ B,
                    const float* __restrict__ bias,
                    float* __restrict__ C,
                    int M, int N, int K) {
    // 128 KiB: buf{0,1} x k-sliced slots {A0,A1,B0,B1} x 8192 bf16 (256r x 32k)
    __shared__ bf16_t lds[65536];

    const int ntn = N / BN;
    const int nwg = gridDim.x;
    // bijective XCD swizzle (8 XCDs)
    const int q = nwg >> 3, r = nwg & 7;
    const int xcd = blockIdx.x & 7, lid = blockIdx.x >> 3;
    const int swz = (xcd < r ? xcd * (q + 1) : r * (q + 1) + (xcd - r) * q) + lid;
    const int tile_m = (swz / ntn) * BM;
    const int tile_n = (swz % ntn) * BN;

    const int tid = threadIdx.x;
    const int lane = tid & 63;
    const int wid = tid >> 6;
    const int wm = wid >> 2;      // 0..1: row half (128 rows)
    const int wn = wid & 3;       // 0..3: col quarter (64 cols)
    const int l31 = lane & 31;
    const int hi2 = lane >> 5;    // 0..1: k-half within k-step
    const int rsw = (l31 >> 1) & 3;  // swizzle row bits 1-2 (spans 8 bank-groups
                                     // with 4*(l31&1) within each 16-lane group)

    // staging source: row = tid>>2 (+128 for 2nd inst); chunk at dest slot
    // c=tid&3 holds global k-chunk j = c ^ ((row>>1)&3) = (tid&3)^((tid>>3)&3)
    const int koff = (((tid & 3) ^ ((tid >> 3) & 3)) << 3);
    const bf16_t* srcA = A + (size_t)(tile_m + (tid >> 2)) * K + koff;
    const bf16_t* srcB = B + (size_t)(tile_n + (tid >> 2)) * K + koff;

    bf16x8 af[4], bf[2];
    f32x16 acc[4][2] = {};

    // prologue: t0 all 4 slots, then t1's B0/A0 (matches steady-state queue);
    // VMW(4) drains t0, keeps t1's slice-0 in flight.
    STAGE(0, srcA);                    // t0.A0
    STAGE(16384, srcB);                // t0.B0
    STAGE(8192, srcA + 32);            // t0.A1
    STAGE(24576, srcB + 32);           // t0.B1
    STAGE(32768 + 16384, srcB + 64);   // t1.B0
    STAGE(32768 + 0, srcA + 64);       // t1.A0
    VMW(4);
    BARF();

    const int npairs = K / 128;        // 2 K-tiles per iteration
    for (int i = 0; i < npairs - 1; ++i) {
        TILE(0, 2 * i, 1, 1, 4);
        TILE(1, 2 * i + 1, 1, 1, 4);
    }
    TILE(0, 2 * npairs - 2, 1, 0, 0);  // t=62: stages t63 slice1; drain all
    TILE(1, 2 * npairs - 1, 0, 0, -1); // t=63: no stages, no waits

    // epilogue: 32x32 C/D layout col=lane&31, row=(reg&3)+8*(reg>>2)+4*(lane>>5)
    float qb[2];
#pragma unroll
    for (int n = 0; n < 2; ++n)
        qb[n] = q16(bias[tile_n + wn * 64 + n * 32 + l31]);
#pragma unroll
    for (int m = 0; m < 4; ++m) {
#pragma unroll
        for (int n = 0; n < 2; ++n) {
            const int gcol = tile_n + wn * 64 + n * 32 + l31;
#pragma unroll
            for (int reg = 0; reg < 16; ++reg) {
                const int grow = tile_m + wm * 128 + m * 32 +
                                 (reg & 3) + 8 * (reg >> 2) + 4 * hi2;
                C[(size_t)grow * N + gcol] = acc[m][n][reg] + qb[n];
            }
        }
    }
}

extern "C" void kernel_launch(void* const* d_in, const int* in_sizes, int n_in,
                              void* d_out, int out_size, void* d_ws, size_t ws_size,
                              hipStream_t stream) {
    const float* inp   = (const float*)d_in[0];
    const float* shift = (const float*)d_in[1];
    const float* sign_ = (const float*)d_in[2];
    const float* bias  = (const float*)d_in[3];
    float* out = (float*)d_out;

    const int OUT_F = in_sizes[3];              // 4096
    const int IN_F  = in_sizes[1] / OUT_F;      // 4096
    const int Mrows = in_sizes[0] / IN_F;       // 4096

    bf16_t* Aq = (bf16_t*)d_ws;
    bf16_t* Wq = Aq + (size_t)Mrows * IN_F;     // (M*K + N*K)*2 = 67.2 MB of ws

    const int nA = Mrows * IN_F;
    const int nW = OUT_F * IN_F;

    quant_input_kernel<<<2048, 256, 0, stream>>>(inp, Aq, nA >> 2);
    make_weight_kernel<<<2048, 256, 0, stream>>>(shift, sign_, Wq, nW >> 2);

    dim3 grid((Mrows / BM) * (OUT_F / BN));
    gemm256_kernel<<<grid, 512, 0, stream>>>(Aq, Wq, bias, out,
                                             Mrows, OUT_F, IN_F);
}